// Round 9
// baseline (137.945 us; speedup 1.0000x reference)
//
#include <hip/hip_runtime.h>
#include <stdint.h>

#define BATCH 32768
#define DIM   512
#define KCLS  512

typedef __bf16    bf16x8 __attribute__((ext_vector_type(8)));
typedef float     f32x4  __attribute__((ext_vector_type(4)));
typedef float     f32x8  __attribute__((ext_vector_type(8)));
typedef uint16_t  u16x8  __attribute__((ext_vector_type(8)));

__device__ __forceinline__ uint16_t f2bf(float f) {
    // RTNE fp32 -> bf16
    uint32_t u = __float_as_uint(f);
    u += 0x7FFFu + ((u >> 16) & 1u);
    return (uint16_t)(u >> 16);
}

#define MFMA(a, b, c) __builtin_amdgcn_mfma_f32_16x16x32_bf16((a), (b), (c), 0, 0, 0)

// ---------------------------------------------------------------------------
// Prep: means (K x D fp32) -> bf16 pre-swizzled into MFMA B-fragment order.
// B-frag for mfma_f32_16x16x32_bf16: B[k = 8*(lane>>4)+j][n = lane&15].
// Bsw layout: index = (((c16*16 + ch)*64) + lane)*8, col = 16*c16 + (lane&15),
// k = 32*ch + 8*(lane>>4) + j.  Also computes inv_var/alpha/beta per class.
// ---------------------------------------------------------------------------
__global__ __launch_bounds__(256) void gmm_prep(
    const float* __restrict__ means,
    const float* __restrict__ log_vars,
    const float* __restrict__ log_weights,
    uint16_t* __restrict__ Bsw,
    float* __restrict__ invv_a,
    float* __restrict__ alpha_a,
    float* __restrict__ beta_a)
{
    const int k = blockIdx.x * 4 + (threadIdx.x >> 6);  // class index
    const int l = threadIdx.x & 63;                     // lane: elems 8l..8l+7

    const float* mrow = means + (size_t)k * DIM + l * 8;
    f32x4 v0 = *(const f32x4*)(mrow);
    f32x4 v1 = *(const f32x4*)(mrow + 4);

    u16x8 pk;
    pk[0] = f2bf(v0[0]); pk[1] = f2bf(v0[1]); pk[2] = f2bf(v0[2]); pk[3] = f2bf(v0[3]);
    pk[4] = f2bf(v1[0]); pk[5] = f2bf(v1[1]); pk[6] = f2bf(v1[2]); pk[7] = f2bf(v1[3]);

    const int c16 = k >> 4, r = k & 15, ch = l >> 2, hh = l & 3;
    *(u16x8*)(Bsw + ((((c16 * 16) + ch) * 64) + (hh * 16 + r)) * 8) = pk;

    float sq = v0[0]*v0[0] + v0[1]*v0[1] + v0[2]*v0[2] + v0[3]*v0[3]
             + v1[0]*v1[0] + v1[1]*v1[1] + v1[2]*v1[2] + v1[3]*v1[3];
    #pragma unroll
    for (int m = 1; m <= 32; m <<= 1) sq += __shfl_xor(sq, m);

    if (l == 0) {
        const float lv = log_vars[k];
        const float iv = __expf(-lv);
        invv_a[k]  = iv;
        alpha_a[k] = -0.5f * iv;
        beta_a[k]  = -0.5f * (sq * iv + (float)DIM * lv) + log_weights[k];
    }
}

// ---------------------------------------------------------------------------
// Main fused kernel, R11 = R10 (verified 47us structure) + conflict-free
// staging WRITES.
// Diagnosis: SQ_LDS_BANK_CONFLICT = 1.835M cycles, constant across rounds.
// Old staging wrote As at dword (c*2+rt)*256 + hh*64 + r16*4; mod 32 banks
// the c/hh terms vanish -> bank = (r16*4)%32: the 8 threads of a row hit
// the same 4-bank group = 8-way write conflict (~2.9x, m136). Reads
// (lane*16 contiguous) were already conflict-free.
// Fix: inverse-map assignment. Thread t, iter i owns slot s = t + 256*i
// -> LDS byte t*16 + i*4096 (lane-contiguous, conflict-free). Inverting
// the A-frag layout map (r16=s&15, h=(s>>4)&3, rt=(s>>6)&1, c=s>>7):
// thread (w,lane) loads x[row0+16(w&1)+(lane&15)][64i+32(w>>1)+8(lane>>4)]
// f32x8 — still contiguous; per-wave = 16 rows x 128B segments, coalesced.
// xsq: reduce over h via shfl_xor(16,32), combine col-halves (waves w,w+2)
// through xsq_p2[4][16]. Same instruction counts, same liveness shape.
// Ledger: R4/R10 structure = 47us best; restructures R5-R9 all lost
// (occupancy cliff or allocator spill). This is an index-remap only.
// ---------------------------------------------------------------------------
__global__ __launch_bounds__(256, 2) void gmm_main(
    const float* __restrict__ x,
    const uint16_t* __restrict__ Bsw,
    const float* __restrict__ invv_a,
    const float* __restrict__ alpha_a,
    const float* __restrict__ beta_a,
    float* __restrict__ out)
{
    __shared__ uint16_t As[16384];   // 32 KB
    __shared__ float xsq_p2[4][16];  // [wave][r16] col-half partials
    __shared__ float pmax[4][32];
    __shared__ float psum[4][32];

    const int t    = threadIdx.x;
    const int w    = t >> 6;        // wave -> col group
    const int lane = t & 63;
    const int r16  = lane & 15;
    const int h    = lane >> 4;
    const int row0 = blockIdx.x * 32;

    // ---- B chunk-0 prefetch issued FIRST: completes under the x-stage ----
    const uint16_t* bb = Bsw + (size_t)w * 65536 + (size_t)lane * 8;
    bf16x8 Ba[8], Bb[8];
    #pragma unroll
    for (int ct = 0; ct < 8; ++ct) Ba[ct] = *(const bf16x8*)(bb + ct * 8192);

    // ---- stage x tile -> LDS, conflict-free writes (slot s = t + 256*i) ----
    {
        const int srow  = 16 * (w & 1) + r16;          // row this thread stages
        const int cbase = 32 * (w >> 1) + 8 * h;       // col base within 64-block
        const float* xr = x + (size_t)(row0 + srow) * DIM + cbase;
        uint16_t* wp = As + (size_t)t * 8;             // byte t*16, lane-contiguous
        float xsq_p = 0.f;
        #pragma unroll
        for (int i = 0; i < 8; ++i) {
            f32x8 v = *(const f32x8*)(xr + 64 * i);
            u16x8 pk;
            #pragma unroll
            for (int j = 0; j < 8; ++j) { xsq_p += v[j] * v[j]; pk[j] = f2bf(v[j]); }
            *(u16x8*)(wp + 2048 * i) = pk;             // s=t+256i -> idx16 t*8+2048i
        }
        // sum over h (lane bits 4,5); r16 and wave preserved
        xsq_p += __shfl_xor(xsq_p, 16);
        xsq_p += __shfl_xor(xsq_p, 32);
        if (lane < 16) xsq_p2[w][r16] = xsq_p;         // col-half partial
    }
    __syncthreads();

    f32x4 acc[2][8];
    #pragma unroll
    for (int rt = 0; rt < 2; ++rt)
        #pragma unroll
        for (int ct = 0; ct < 8; ++ct)
            acc[rt][ct] = (f32x4){0.f, 0.f, 0.f, 0.f};

    const uint16_t* ab = As + (size_t)lane * 8;     // LDS, frag base

    // ---- software-pipelined K-loop (16 chunks, 2 per unrolled iter) ----
    bf16x8 Aa0, Aa1, Ab0, Ab1;
    Aa0 = *(const bf16x8*)(ab);
    Aa1 = *(const bf16x8*)(ab + 512);

    #pragma unroll
    for (int c2 = 0; c2 < 8; ++c2) {
        const int k1 = 2 * c2 + 1, k2 = 2 * c2 + 2;

        // A prefetch for k1 (LDS), then B-prefetch interleaved 1:1 with MFMAs
        Ab0 = *(const bf16x8*)(ab + k1 * 1024);
        Ab1 = *(const bf16x8*)(ab + k1 * 1024 + 512);
        #pragma unroll
        for (int ct = 0; ct < 8; ++ct) {
            Bb[ct] = *(const bf16x8*)(bb + ct * 8192 + k1 * 512);
            acc[0][ct] = MFMA(Aa0, Ba[ct], acc[0][ct]);
            acc[1][ct] = MFMA(Aa1, Ba[ct], acc[1][ct]);
        }

        if (c2 < 7) {
            Aa0 = *(const bf16x8*)(ab + k2 * 1024);
            Aa1 = *(const bf16x8*)(ab + k2 * 1024 + 512);
        }
        #pragma unroll
        for (int ct = 0; ct < 8; ++ct) {
            if (c2 < 7) Ba[ct] = *(const bf16x8*)(bb + ct * 8192 + k2 * 512);
            acc[0][ct] = MFMA(Ab0, Bb[ct], acc[0][ct]);
            acc[1][ct] = MFMA(Ab1, Bb[ct], acc[1][ct]);
        }
    }

    // ---- per-column affine params (L2-hot) ----
    float invv[8], alf[8], bet[8];
    #pragma unroll
    for (int ct = 0; ct < 8; ++ct) {
        const int col = 128 * w + 16 * ct + r16;
        invv[ct] = invv_a[col];
        alf[ct]  = alpha_a[col];
        bet[ct]  = beta_a[col];
    }
    float xsq[2][4];
    #pragma unroll
    for (int rt = 0; rt < 2; ++rt)
        #pragma unroll
        for (int reg = 0; reg < 4; ++reg)
            xsq[rt][reg] = xsq_p2[rt][4 * h + reg] + xsq_p2[rt + 2][4 * h + reg];

    // ---- logits + per-row max (C layout: col=lane&15, row=4*(lane>>4)+reg) ----
    float mr[2][4];
    #pragma unroll
    for (int rt = 0; rt < 2; ++rt) {
        #pragma unroll
        for (int reg = 0; reg < 4; ++reg) {
            float m = -1e30f;
            #pragma unroll
            for (int ct = 0; ct < 8; ++ct) {
                const float v = acc[rt][ct][reg] * invv[ct] + (alf[ct] * xsq[rt][reg] + bet[ct]);
                acc[rt][ct][reg] = v;
                m = fmaxf(m, v);
            }
            m = fmaxf(m, __shfl_xor(m, 1));
            m = fmaxf(m, __shfl_xor(m, 2));
            m = fmaxf(m, __shfl_xor(m, 4));
            m = fmaxf(m, __shfl_xor(m, 8));
            mr[rt][reg] = m;
        }
    }
    if (r16 == 0) {
        #pragma unroll
        for (int rt = 0; rt < 2; ++rt)
            #pragma unroll
            for (int reg = 0; reg < 4; ++reg)
                pmax[w][16 * rt + 4 * h + reg] = mr[rt][reg];
    }
    __syncthreads();

    // ---- exp + per-row sum ----
    float sr[2][4];
    #pragma unroll
    for (int rt = 0; rt < 2; ++rt) {
        #pragma unroll
        for (int reg = 0; reg < 4; ++reg) {
            const int rl = 16 * rt + 4 * h + reg;
            const float m = fmaxf(fmaxf(pmax[0][rl], pmax[1][rl]),
                                  fmaxf(pmax[2][rl], pmax[3][rl]));
            float s = 0.f;
            #pragma unroll
            for (int ct = 0; ct < 8; ++ct) {
                const float e = __expf(acc[rt][ct][reg] - m);
                acc[rt][ct][reg] = e;
                s += e;
            }
            s += __shfl_xor(s, 1);
            s += __shfl_xor(s, 2);
            s += __shfl_xor(s, 4);
            s += __shfl_xor(s, 8);
            sr[rt][reg] = s;
        }
    }
    if (r16 == 0) {
        #pragma unroll
        for (int rt = 0; rt < 2; ++rt)
            #pragma unroll
            for (int reg = 0; reg < 4; ++reg)
                psum[w][16 * rt + 4 * h + reg] = sr[rt][reg];
    }
    __syncthreads();

    // ---- normalize + store ----
    #pragma unroll
    for (int rt = 0; rt < 2; ++rt) {
        #pragma unroll
        for (int reg = 0; reg < 4; ++reg) {
            const int rl = 16 * rt + 4 * h + reg;
            const float tot = (psum[0][rl] + psum[1][rl]) + (psum[2][rl] + psum[3][rl]);
            const float rinv = 1.0f / tot;
            float* orow = out + (size_t)(row0 + rl) * KCLS + 128 * w + r16;
            #pragma unroll
            for (int ct = 0; ct < 8; ++ct)
                orow[16 * ct] = acc[rt][ct][reg] * rinv;
        }
    }
}

extern "C" void kernel_launch(void* const* d_in, const int* in_sizes, int n_in,
                              void* d_out, int out_size, void* d_ws, size_t ws_size,
                              hipStream_t stream) {
    (void)in_sizes; (void)n_in; (void)out_size; (void)ws_size;
    const float* x           = (const float*)d_in[0];
    const float* means       = (const float*)d_in[1];
    const float* log_vars    = (const float*)d_in[2];
    const float* log_weights = (const float*)d_in[3];
    float* out = (float*)d_out;

    // ws: [0, 512KB) swizzled bf16 means; then inv_var/alpha/beta (512 f32 each)
    uint16_t* Bsw = (uint16_t*)d_ws;
    float* invv_a  = (float*)((char*)d_ws + (512u << 10));
    float* alpha_a = invv_a + KCLS;
    float* beta_a  = alpha_a + KCLS;

    gmm_prep<<<KCLS / 4, 256, 0, stream>>>(means, log_vars, log_weights,
                                           Bsw, invv_a, alpha_a, beta_a);
    gmm_main<<<BATCH / 32, 256, 0, stream>>>(x, Bsw, invv_a, alpha_a, beta_a, out);
}

// Round 10
// 136.485 us; speedup vs baseline: 1.0107x; 1.0107x over previous
//
#include <hip/hip_runtime.h>
#include <stdint.h>

#define BATCH 32768
#define DIM   512
#define KCLS  512

typedef __bf16    bf16x8 __attribute__((ext_vector_type(8)));
typedef float     f32x4  __attribute__((ext_vector_type(4)));
typedef float     f32x8  __attribute__((ext_vector_type(8)));
typedef uint16_t  u16x8  __attribute__((ext_vector_type(8)));

__device__ __forceinline__ uint16_t f2bf(float f) {
    // RTNE fp32 -> bf16
    uint32_t u = __float_as_uint(f);
    u += 0x7FFFu + ((u >> 16) & 1u);
    return (uint16_t)(u >> 16);
}

#define MFMA(a, b, c) __builtin_amdgcn_mfma_f32_16x16x32_bf16((a), (b), (c), 0, 0, 0)

// ---------------------------------------------------------------------------
// Prep: means (K x D fp32) -> bf16 pre-swizzled into MFMA B-fragment order.
// B-frag for mfma_f32_16x16x32_bf16: B[k = 8*(lane>>4)+j][n = lane&15].
// Bsw layout: index = (((c16*16 + ch)*64) + lane)*8, col = 16*c16 + (lane&15),
// k = 32*ch + 8*(lane>>4) + j.  Also computes inv_var/alpha/beta per class.
// ---------------------------------------------------------------------------
__global__ __launch_bounds__(256) void gmm_prep(
    const float* __restrict__ means,
    const float* __restrict__ log_vars,
    const float* __restrict__ log_weights,
    uint16_t* __restrict__ Bsw,
    float* __restrict__ invv_a,
    float* __restrict__ alpha_a,
    float* __restrict__ beta_a)
{
    const int k = blockIdx.x * 4 + (threadIdx.x >> 6);  // class index
    const int l = threadIdx.x & 63;                     // lane: elems 8l..8l+7

    const float* mrow = means + (size_t)k * DIM + l * 8;
    f32x4 v0 = *(const f32x4*)(mrow);
    f32x4 v1 = *(const f32x4*)(mrow + 4);

    u16x8 pk;
    pk[0] = f2bf(v0[0]); pk[1] = f2bf(v0[1]); pk[2] = f2bf(v0[2]); pk[3] = f2bf(v0[3]);
    pk[4] = f2bf(v1[0]); pk[5] = f2bf(v1[1]); pk[6] = f2bf(v1[2]); pk[7] = f2bf(v1[3]);

    const int c16 = k >> 4, r = k & 15, ch = l >> 2, hh = l & 3;
    *(u16x8*)(Bsw + ((((c16 * 16) + ch) * 64) + (hh * 16 + r)) * 8) = pk;

    float sq = v0[0]*v0[0] + v0[1]*v0[1] + v0[2]*v0[2] + v0[3]*v0[3]
             + v1[0]*v1[0] + v1[1]*v1[1] + v1[2]*v1[2] + v1[3]*v1[3];
    #pragma unroll
    for (int m = 1; m <= 32; m <<= 1) sq += __shfl_xor(sq, m);

    if (l == 0) {
        const float lv = log_vars[k];
        const float iv = __expf(-lv);
        invv_a[k]  = iv;
        alpha_a[k] = -0.5f * iv;
        beta_a[k]  = -0.5f * (sq * iv + (float)DIM * lv) + log_weights[k];
    }
}

// ---------------------------------------------------------------------------
// Main fused kernel, R12 = R10 (verified 47us/135us optimum) + NON-TEMPORAL
// epilogue stores.
// Post-mortem R11: conflict-free staging writes zeroed SQ_LDS_BANK_CONFLICT
// (1.835M->0) but cost 1.7us — the remap degraded staging's GLOBAL read
// coalescing from 256B to 32B segments; the LDS conflicts were fully
// latency-hidden. Reverted to R10's staging (conflicts accepted).
// R12's single delta: out is write-once, never re-read; normal stores
// write-allocate into L2 and can evict the L2-resident 512KB Bsw that the
// next block-round re-reads (4 rounds/CU). Eviction is invisible in
// FETCH_SIZE (B re-fetch comes from L3, not HBM). __builtin_nontemporal_store
// sets the nt/no-allocate bit: out bypasses L2, Bsw stays warm. Zero
// register/structure change — same kernel to the allocator.
// Ledger: R5-R9 restructures all lost (occupancy cliff / allocator spill);
// hoist neutral; conflict-fix negative. This is the last untried
// mechanistically-motivated in-structure lever.
// ---------------------------------------------------------------------------
__global__ __launch_bounds__(256, 2) void gmm_main(
    const float* __restrict__ x,
    const uint16_t* __restrict__ Bsw,
    const float* __restrict__ invv_a,
    const float* __restrict__ alpha_a,
    const float* __restrict__ beta_a,
    float* __restrict__ out)
{
    __shared__ uint16_t As[16384];   // 32 KB
    __shared__ float xsq_lds[32];
    __shared__ float pmax[4][32];
    __shared__ float psum[4][32];

    const int t    = threadIdx.x;
    const int w    = t >> 6;        // wave -> col group
    const int lane = t & 63;
    const int r16  = lane & 15;
    const int h    = lane >> 4;
    const int row0 = blockIdx.x * 32;

    // ---- B chunk-0 prefetch issued FIRST: completes under the x-stage ----
    const uint16_t* bb = Bsw + (size_t)w * 65536 + (size_t)lane * 8;
    bf16x8 Ba[8], Bb[8];
    #pragma unroll
    for (int ct = 0; ct < 8; ++ct) Ba[ct] = *(const bf16x8*)(bb + ct * 8192);

    // ---- stage x tile -> LDS (fragment order) + xsq ----
    // (R10 pattern: 8 threads/row, 256B-contiguous global segments per instr.
    //  LDS write is an 8-way bank conflict but fully latency-hidden — R11
    //  proved fixing it costs more in global coalescing than it saves.)
    {
        const int srow = t >> 3, sp = t & 7;         // 8 threads per row
        const int rt_s = srow >> 4, r16_s = srow & 15;
        const float* xr = x + (size_t)(row0 + srow) * DIM;
        float xsq_p = 0.f;
        #pragma unroll
        for (int i = 0; i < 8; ++i) {
            const int o = sp + 8 * i;                // k-octet 0..63
            f32x8 v = *(const f32x8*)(xr + 8 * o);
            u16x8 pk;
            #pragma unroll
            for (int j = 0; j < 8; ++j) { xsq_p += v[j] * v[j]; pk[j] = f2bf(v[j]); }
            const int c = o >> 2, hh = o & 3;
            *(u16x8*)&As[(((c * 2 + rt_s) * 64) + hh * 16 + r16_s) * 8] = pk;
        }
        xsq_p += __shfl_xor(xsq_p, 1);
        xsq_p += __shfl_xor(xsq_p, 2);
        xsq_p += __shfl_xor(xsq_p, 4);
        if (sp == 0) xsq_lds[srow] = xsq_p;
    }
    __syncthreads();

    f32x4 acc[2][8];
    #pragma unroll
    for (int rt = 0; rt < 2; ++rt)
        #pragma unroll
        for (int ct = 0; ct < 8; ++ct)
            acc[rt][ct] = (f32x4){0.f, 0.f, 0.f, 0.f};

    const uint16_t* ab = As + (size_t)lane * 8;     // LDS, frag base

    // ---- software-pipelined K-loop (16 chunks, 2 per unrolled iter) ----
    bf16x8 Aa0, Aa1, Ab0, Ab1;
    Aa0 = *(const bf16x8*)(ab);
    Aa1 = *(const bf16x8*)(ab + 512);

    #pragma unroll
    for (int c2 = 0; c2 < 8; ++c2) {
        const int k1 = 2 * c2 + 1, k2 = 2 * c2 + 2;

        // A prefetch for k1 (LDS), then B-prefetch interleaved 1:1 with MFMAs
        Ab0 = *(const bf16x8*)(ab + k1 * 1024);
        Ab1 = *(const bf16x8*)(ab + k1 * 1024 + 512);
        #pragma unroll
        for (int ct = 0; ct < 8; ++ct) {
            Bb[ct] = *(const bf16x8*)(bb + ct * 8192 + k1 * 512);
            acc[0][ct] = MFMA(Aa0, Ba[ct], acc[0][ct]);
            acc[1][ct] = MFMA(Aa1, Ba[ct], acc[1][ct]);
        }

        if (c2 < 7) {
            Aa0 = *(const bf16x8*)(ab + k2 * 1024);
            Aa1 = *(const bf16x8*)(ab + k2 * 1024 + 512);
        }
        #pragma unroll
        for (int ct = 0; ct < 8; ++ct) {
            if (c2 < 7) Ba[ct] = *(const bf16x8*)(bb + ct * 8192 + k2 * 512);
            acc[0][ct] = MFMA(Ab0, Bb[ct], acc[0][ct]);
            acc[1][ct] = MFMA(Ab1, Bb[ct], acc[1][ct]);
        }
    }

    // ---- per-column affine params (L2-hot; after K-loop to cap pressure) ----
    float invv[8], alf[8], bet[8];
    #pragma unroll
    for (int ct = 0; ct < 8; ++ct) {
        const int col = 128 * w + 16 * ct + r16;
        invv[ct] = invv_a[col];
        alf[ct]  = alpha_a[col];
        bet[ct]  = beta_a[col];
    }
    float xsq[2][4];
    #pragma unroll
    for (int rt = 0; rt < 2; ++rt)
        #pragma unroll
        for (int reg = 0; reg < 4; ++reg)
            xsq[rt][reg] = xsq_lds[16 * rt + 4 * h + reg];

    // ---- logits + per-row max (C layout: col=lane&15, row=4*(lane>>4)+reg) ----
    float mr[2][4];
    #pragma unroll
    for (int rt = 0; rt < 2; ++rt) {
        #pragma unroll
        for (int reg = 0; reg < 4; ++reg) {
            float m = -1e30f;
            #pragma unroll
            for (int ct = 0; ct < 8; ++ct) {
                const float v = acc[rt][ct][reg] * invv[ct] + (alf[ct] * xsq[rt][reg] + bet[ct]);
                acc[rt][ct][reg] = v;
                m = fmaxf(m, v);
            }
            m = fmaxf(m, __shfl_xor(m, 1));
            m = fmaxf(m, __shfl_xor(m, 2));
            m = fmaxf(m, __shfl_xor(m, 4));
            m = fmaxf(m, __shfl_xor(m, 8));
            mr[rt][reg] = m;
        }
    }
    if (r16 == 0) {
        #pragma unroll
        for (int rt = 0; rt < 2; ++rt)
            #pragma unroll
            for (int reg = 0; reg < 4; ++reg)
                pmax[w][16 * rt + 4 * h + reg] = mr[rt][reg];
    }
    __syncthreads();

    // ---- exp + per-row sum ----
    float sr[2][4];
    #pragma unroll
    for (int rt = 0; rt < 2; ++rt) {
        #pragma unroll
        for (int reg = 0; reg < 4; ++reg) {
            const int rl = 16 * rt + 4 * h + reg;
            const float m = fmaxf(fmaxf(pmax[0][rl], pmax[1][rl]),
                                  fmaxf(pmax[2][rl], pmax[3][rl]));
            float s = 0.f;
            #pragma unroll
            for (int ct = 0; ct < 8; ++ct) {
                const float e = __expf(acc[rt][ct][reg] - m);
                acc[rt][ct][reg] = e;
                s += e;
            }
            s += __shfl_xor(s, 1);
            s += __shfl_xor(s, 2);
            s += __shfl_xor(s, 4);
            s += __shfl_xor(s, 8);
            sr[rt][reg] = s;
        }
    }
    if (r16 == 0) {
        #pragma unroll
        for (int rt = 0; rt < 2; ++rt)
            #pragma unroll
            for (int reg = 0; reg < 4; ++reg)
                psum[w][16 * rt + 4 * h + reg] = sr[rt][reg];
    }
    __syncthreads();

    // ---- normalize + store (NON-TEMPORAL: out is never re-read; keep L2
    //      clean so the next block-round's Bsw stream stays resident) ----
    #pragma unroll
    for (int rt = 0; rt < 2; ++rt) {
        #pragma unroll
        for (int reg = 0; reg < 4; ++reg) {
            const int rl = 16 * rt + 4 * h + reg;
            const float tot = (psum[0][rl] + psum[1][rl]) + (psum[2][rl] + psum[3][rl]);
            const float rinv = 1.0f / tot;
            float* orow = out + (size_t)(row0 + rl) * KCLS + 128 * w + r16;
            #pragma unroll
            for (int ct = 0; ct < 8; ++ct)
                __builtin_nontemporal_store(acc[rt][ct][reg] * rinv, &orow[16 * ct]);
        }
    }
}

extern "C" void kernel_launch(void* const* d_in, const int* in_sizes, int n_in,
                              void* d_out, int out_size, void* d_ws, size_t ws_size,
                              hipStream_t stream) {
    (void)in_sizes; (void)n_in; (void)out_size; (void)ws_size;
    const float* x           = (const float*)d_in[0];
    const float* means       = (const float*)d_in[1];
    const float* log_vars    = (const float*)d_in[2];
    const float* log_weights = (const float*)d_in[3];
    float* out = (float*)d_out;

    // ws: [0, 512KB) swizzled bf16 means; then inv_var/alpha/beta (512 f32 each)
    uint16_t* Bsw = (uint16_t*)d_ws;
    float* invv_a  = (float*)((char*)d_ws + (512u << 10));
    float* alpha_a = invv_a + KCLS;
    float* beta_a  = alpha_a + KCLS;

    gmm_prep<<<KCLS / 4, 256, 0, stream>>>(means, log_vars, log_weights,
                                           Bsw, invv_a, alpha_a, beta_a);
    gmm_main<<<BATCH / 32, 256, 0, stream>>>(x, Bsw, invv_a, alpha_a, beta_a, out);
}